// Round 10
// baseline (739.727 us; speedup 1.0000x reference)
//
#include <hip/hip_runtime.h>
#include <math.h>

// Problem constants
#define NB    16            // batches
#define NPB   (512*512)     // elements per batch
#define NBINS 64
#define MMB   64            // minmax blocks per batch (grid 1024 = 4/CU)
#define CB    64            // hist chunks per (tensor,batch) -> grid 2*16*64 = 2048
#define EPSF  1e-8f
#define QF    0.84932180517f   // sqrt(0.5*log2(e)); exp(-d^2/2) = exp2(-(q*d)^2)
#define L2E   1.44269504089f   // log2(e)
#define LN2   0.69314718056f

// R27: scatter retry with RAW ds_add_f32. Dense chain is stuck at ~34 us
// across 3 structural variants (R22/R25/R26) at <=50% VALU efficiency ->
// not issue-bound. R18's scatter failed (673 us, VALUBusy 1.7%) with ~200
// cyc/atomic NO-overlap -- suspect emission (generic-ptr atomicAdd -> flat
// path or rtn+wait), not the DS pipe (reads measure 3-6 cyc). R18 PASSED
// correctness (absmax 0.0) so the radius-8 window math + epilogue are
// proven; this round swaps ONLY the atomic emission: inline-asm
// ds_add_f32 (no-rtn, unwaited; one s_waitcnt lgkmcnt(0) before the final
// barrier). LDS hist [96 rows x 64 lane-cols], col=lane -> 2-way bank
// aliasing (free, m136). Per point: ~40 VALU + 3 exp2 + 16 DS.
// If pipelined (4-6cyc): hist ~14-20 us. If not: branch closed for good.

// ws layout: mmn[1024] | mmx[1024] | hist[2][16][64]

// ---------- pass 1: per-batch block-level min/max (also zeroes hist) ----------
__global__ __launch_bounds__(256) void minmax_k(const float4* __restrict__ tgt,
                                                float* __restrict__ mmn,
                                                float* __restrict__ mmx,
                                                float* __restrict__ hist) {
    const int batch = blockIdx.x / MMB, sub = blockIdx.x % MMB;
    if (sub == 0 && threadIdx.x < 128) {
        const int tens = threadIdx.x >> 6, lane = threadIdx.x & 63;
        hist[(tens * NB + batch) * NBINS + lane] = 0.0f;
    }

    const int F4 = NPB / 4 / MMB;              // 1024 float4 per block
    const float4* p = tgt + (size_t)batch * (NPB / 4) + (size_t)sub * F4;
    float mn = 3.4e38f, mx = -3.4e38f;
    #pragma unroll
    for (int i = 0; i < F4 / 256; ++i) {       // 4 iterations
        float4 v = p[i * 256 + threadIdx.x];
        mn = fminf(mn, fminf(fminf(v.x, v.y), fminf(v.z, v.w)));
        mx = fmaxf(mx, fmaxf(fmaxf(v.x, v.y), fmaxf(v.z, v.w)));
    }
    #pragma unroll
    for (int o = 1; o < 64; o <<= 1) {
        mn = fminf(mn, __shfl_xor(mn, o));
        mx = fmaxf(mx, __shfl_xor(mx, o));
    }
    __shared__ float smn[4], smx[4];
    const int wave = threadIdx.x >> 6, lane = threadIdx.x & 63;
    if (lane == 0) { smn[wave] = mn; smx[wave] = mx; }
    __syncthreads();
    if (threadIdx.x == 0) {
        mmn[blockIdx.x] = fminf(fminf(smn[0], smn[1]), fminf(smn[2], smn[3]));
        mmx[blockIdx.x] = fmaxf(fmaxf(smx[0], smx[1]), fmaxf(smx[2], smx[3]));
    }
}

#define GROWS 96            // 94 rows used: bin b at row b+15

// ---------- per-point scatter of 16 bins via raw ds_add_f32 ----------
// u = x*s64 + b0 puts bin centers at integer u. ibin = rint(clamp(u)),
// d = uc - ibin in [-0.5,0.5]. E(ibin+j) = A * r^j * C_j, A = e^{-d^2/2},
// r = e^d, C_j = e^{-j^2/2} literals. Window j in [-8,7] -> rows
// ibin+7..ibin+22 (row = byte offset/256). Clamp [-7.49,71.49] -> rows
// 0..93 in a 96-row LDS hist; clamped points hit guard rows only
// (weight reaching a real bin <= e^-28). Math identical to R18 (absmax 0).
#define DSADD(off, val) \
    asm volatile("ds_add_f32 %0, %1 offset:" #off :: "v"(addr), "v"(val))

__device__ __forceinline__ void point16(float xin, float s64, float b0,
                                        unsigned int lbl) {   // ldsbase+lane*4
    const float C1 = 0.60653065971f,    C2 = 0.13533528324f,
                C3 = 0.01110899654f,    C4 = 3.35462627903e-4f,
                C5 = 3.72665317208e-6f, C6 = 1.52299797447e-8f,
                C7 = 2.28973484833e-11f, C8 = 1.26641655490e-14f;
    float u  = fmaf(xin, s64, b0);
    float uc = __builtin_amdgcn_fmed3f(u, -7.49f, 71.49f);
    float fb = rintf(uc);
    float d  = uc - fb;
    unsigned int addr = lbl + (((int)fb + 7) << 8);  // window row 0 byte addr
    float x  = d * L2E;
    float r  = __builtin_amdgcn_exp2f(x);
    float ri = __builtin_amdgcn_exp2f(-x);
    float t  = d * QF;
    float A  = __builtin_amdgcn_exp2f(-(t * t));
    DSADD(2048, A);                                  // center bin, row 8
    float T = A, U = A;
    float w;
    T *= r;  w = T * C1; DSADD(2304, w);
    T *= r;  w = T * C2; DSADD(2560, w);
    T *= r;  w = T * C3; DSADD(2816, w);
    T *= r;  w = T * C4; DSADD(3072, w);
    T *= r;  w = T * C5; DSADD(3328, w);
    T *= r;  w = T * C6; DSADD(3584, w);
    T *= r;  w = T * C7; DSADD(3840, w);
    U *= ri; w = U * C1; DSADD(1792, w);
    U *= ri; w = U * C2; DSADD(1536, w);
    U *= ri; w = U * C3; DSADD(1280, w);
    U *= ri; w = U * C4; DSADD(1024, w);
    U *= ri; w = U * C5; DSADD(768, w);
    U *= ri; w = U * C6; DSADD(512, w);
    U *= ri; w = U * C7; DSADD(256, w);
    U *= ri; w = U * C8; DSADD(0, w);
}

// ---------- pass 2: scatter histogram, one visit per point ----------
__global__ __launch_bounds__(256) void hist_k(const float4* __restrict__ pred,
                                              const float4* __restrict__ tgt,
                                              const float* __restrict__ mmn,
                                              const float* __restrict__ mmx,
                                              float* __restrict__ hist) {
    __shared__ float hl[GROWS * 64];
    const int blk   = blockIdx.x;
    const int tens  = blk & 1;
    const int batch = (blk >> 1) & (NB - 1);
    const int chunk = blk >> 5;                      // 0..CB-1
    const int tid   = threadIdx.x;
    const int lane  = tid & 63;
    const int q     = tid >> 6;                      // wave index

    // zero LDS histogram (1536 float4)
    float4* z = (float4*)hl;
    #pragma unroll
    for (int i = 0; i < 6; ++i) z[i * 256 + tid] = make_float4(0.f, 0.f, 0.f, 0.f);

    const int F4C = NPB / 4 / CB;                    // 1024 float4 per chunk
    const float4* __restrict__ src = (tens ? tgt : pred)
        + (size_t)batch * (NPB / 4) + (size_t)chunk * F4C;

    // issue first data load before the prologue reduction (overlap)
    float4 v = src[tid];

    // lane-parallel reduce of this batch's 64 minmax partials
    float vmin = mmn[batch * MMB + lane];
    float vmax = mmx[batch * MMB + lane];
    #pragma unroll
    for (int o = 1; o < 64; o <<= 1) {
        vmin = fminf(vmin, __shfl_xor(vmin, o));
        vmax = fmaxf(vmax, __shfl_xor(vmax, o));
    }
    const float s64 = 64.0f / (vmax - vmin + EPSF);
    const float b0  = fmaf(-vmin, s64, -0.5f);       // u = x*s64 + b0

    // LDS byte address of this lane's column (generic->LDS low-32 trick;
    // hl is the only __shared__ object -> offset 0-based)
    const unsigned int lbl = (unsigned int)(uintptr_t)hl + (lane << 2);

    __syncthreads();                                 // LDS zero visible

    #pragma unroll 1
    for (int it = 0; it < 4; ++it) {                 // 4 float4 per thread
        float4 vn = src[(it < 3 ? (it + 1) * 256 : 0) + tid];
        point16(v.x, s64, b0, lbl);
        point16(v.y, s64, b0, lbl);
        point16(v.z, s64, b0, lbl);
        point16(v.w, s64, b0, lbl);
        v = vn;
    }
    // drain untracked asm ds_adds, then barrier
    asm volatile("s_waitcnt lgkmcnt(0)" ::: "memory");
    __syncthreads();                                 // all scatters done

    // reduce real bins (rows 15..78) over 64 columns; thread (q,bin) sums
    // 16 columns on a rotated diagonal (bank = col%32, 2-way, conflict-free)
    const int bin  = lane;
    const int brow = (bin + 15) << 6;
    float part = 0.f;
    #pragma unroll
    for (int i = 0; i < 16; ++i) {
        int col = (bin + (q << 4) + i) & 63;
        part += hl[brow + col];
    }
    // stage quarter-partials in rows 0..3 (disjoint from rows 15..78 reads)
    hl[q * 64 + bin] = part;
    __syncthreads();
    if (tid < 64) {
        float s = hl[bin] + hl[64 + bin] + hl[128 + bin] + hl[192 + bin];
        unsafeAtomicAdd(&hist[(tens * NB + batch) * NBINS + bin], s);
    }
}

// ---------- pass 3: KL (fp32, v_log), tiny ----------
__global__ __launch_bounds__(256) void final_k(const float* __restrict__ hist,
                                               float* __restrict__ out) {
    const int lane = threadIdx.x & 63, wave = threadIdx.x >> 6;
    __shared__ float wacc[4];
    float a = 0.0f;
    for (int b = wave; b < NB; b += 4) {
        float hp = hist[b * NBINS + lane];
        float ht = hist[(NB + b) * NBINS + lane];
        float sp = hp, st = ht;
        #pragma unroll
        for (int o = 1; o < 64; o <<= 1) {
            sp += __shfl_xor(sp, o);
            st += __shfl_xor(st, o);
        }
        float pp = hp / (sp + EPSF);
        float pt = ht / (st + EPSF);
        float term = pt * ((__builtin_amdgcn_logf(pt + EPSF)
                          - __builtin_amdgcn_logf(pp + EPSF)) * LN2);
        #pragma unroll
        for (int o = 1; o < 64; o <<= 1) term += __shfl_xor(term, o);
        a += term;
    }
    if (lane == 0) wacc[wave] = a;
    __syncthreads();
    if (threadIdx.x == 0)
        out[0] = 0.1f * (wacc[0] + wacc[1] + wacc[2] + wacc[3]) / (float)NB;
}

extern "C" void kernel_launch(void* const* d_in, const int* in_sizes, int n_in,
                              void* d_out, int out_size, void* d_ws, size_t ws_size,
                              hipStream_t stream) {
    const float* pred = (const float*)d_in[0];
    const float* tgt  = (const float*)d_in[1];
    float* mmn  = (float*)d_ws;
    float* mmx  = mmn + NB * MMB;
    float* hist = mmx + NB * MMB;
    float* out  = (float*)d_out;

    minmax_k<<<NB * MMB, 256, 0, stream>>>((const float4*)tgt, mmn, mmx, hist);
    hist_k  <<<2 * NB * CB, 256, 0, stream>>>((const float4*)pred, (const float4*)tgt,
                                              mmn, mmx, hist);
    final_k <<<1, 256, 0, stream>>>(hist, out);
}

// Round 11
// 143.369 us; speedup vs baseline: 5.1596x; 5.1596x over previous
//
#include <hip/hip_runtime.h>
#include <math.h>

// Problem constants
#define NB    16            // batches
#define NPB   (512*512)     // elements per batch
#define NBINS 64
#define MMB   64            // minmax blocks per batch (grid 1024 = 4/CU)
#define CB    64            // hist chunks per (tensor,batch) -> grid 2*16*64 = 2048
#define EPSF  1e-8f
#define QF    0.84932180517f   // sqrt(0.5*log2(e)); exp(-d^2/2) = exp2(-(q*d)^2)
#define L2E   1.44269504089f   // log2(e)
#define LN2   0.69314718056f
#define K16   1.12535175e-7f   // e^-16
#define K16I  8886110.5f       // e^+16
#define K32   1.26641655e-14f  // e^-32
#define K32I  7.8962960e13f    // e^+32
#define K48   1.42516408e-21f  // e^-48
#define K48I  7.01673591e20f   // e^+48

// R28 = R26 dense (102.7 us) + final_k folded into hist_k via last-block-
// done. R27 closed the scatter branch for good: raw ds_add_f32 identical
// 674 us -> LDS atomics resolve ~3cyc/LANE serially (~200 cyc/wave-instr),
// HW property. Remaining budget: fill ~44 (harness) + minmax ~7 + hist ~34
// + final ~4 + gaps ~14. This round removes the 3rd dispatch: each hist
// block bumps a device-scope counter after its bin atomics (__syncthreads
// drains them: compiler emits vmcnt(0) before s_barrier); the block seeing
// old==2047 acquires (__threadfence) and computes KL reading hist via
// agent-scope loads (G16). Counter re-zeroed by minmax_k every launch ->
// graph-replay safe. No co-residency / dispatch-order assumptions.

typedef float v2f __attribute__((ext_vector_type(2)));

#define AG_LOAD(p) __hip_atomic_load((p), __ATOMIC_RELAXED, __HIP_MEMORY_SCOPE_AGENT)

// ws layout: mmn[1024] | mmx[1024] | hist[2][16][64] | cnt[1]

// ---------- pass 1: per-batch block-level min/max (zeroes hist + cnt) ----------
__global__ __launch_bounds__(256) void minmax_k(const float4* __restrict__ tgt,
                                                float* __restrict__ mmn,
                                                float* __restrict__ mmx,
                                                float* __restrict__ hist,
                                                unsigned int* __restrict__ cnt) {
    const int batch = blockIdx.x / MMB, sub = blockIdx.x % MMB;
    if (sub == 0 && threadIdx.x < 128) {
        const int tens = threadIdx.x >> 6, lane = threadIdx.x & 63;
        hist[(tens * NB + batch) * NBINS + lane] = 0.0f;
    }
    if (blockIdx.x == 0 && threadIdx.x == 0) cnt[0] = 0u;

    const int F4 = NPB / 4 / MMB;              // 1024 float4 per block
    const float4* p = tgt + (size_t)batch * (NPB / 4) + (size_t)sub * F4;
    float mn = 3.4e38f, mx = -3.4e38f;
    #pragma unroll
    for (int i = 0; i < F4 / 256; ++i) {       // 4 iterations
        float4 v = p[i * 256 + threadIdx.x];
        mn = fminf(mn, fminf(fminf(v.x, v.y), fminf(v.z, v.w)));
        mx = fmaxf(mx, fmaxf(fmaxf(v.x, v.y), fmaxf(v.z, v.w)));
    }
    #pragma unroll
    for (int o = 1; o < 64; o <<= 1) {
        mn = fminf(mn, __shfl_xor(mn, o));
        mx = fmaxf(mx, __shfl_xor(mx, o));
    }
    __shared__ float smn[4], smx[4];
    const int wave = threadIdx.x >> 6, lane = threadIdx.x & 63;
    if (lane == 0) { smn[wave] = mn; smx[wave] = mx; }
    __syncthreads();
    if (threadIdx.x == 0) {
        mmn[blockIdx.x] = fminf(fminf(smn[0], smn[1]), fminf(smn[2], smn[3]));
        mmx[blockIdx.x] = fmaxf(fmaxf(smx[0], smx[1]), fmaxf(smx[2], smx[3]));
    }
}

// ---------- per-point update of ALL 64 bins, 4 packed anchors ----------
// d = u - 8. Anchor m in {8,24,40,56} covers bins m-8..m+7:
// E(m+i) = A_m * rho_m^i * C_i, A_m = e^{-(d-(m-8))^2/2}, rho_m = e^d * e^{-(m-8)}.
// accA[k] = bins (k, 16+k); accB[k] = bins (32+k, 48+k), k = 0..15.
// Clamp [-30,78]: at bounds max rate e^78 finite, amplitudes underflow to 0;
// clamp only bites where true contribution <= e^-242.
__device__ __forceinline__ void point64(float xin, float s64, float bk8,
                                        v2f* __restrict__ accA,
                                        v2f* __restrict__ accB) {
    const float C1 = 0.60653065971f,    C2 = 0.13533528324f,
                C3 = 0.01110899654f,    C4 = 3.35462627903e-4f,
                C5 = 3.72665317208e-6f, C6 = 1.52299797447e-8f,
                C7 = 2.28973484833e-11f, C8 = 1.26641655490e-14f;
    const v2f c1 = {C1, C1}, c2 = {C2, C2}, c3 = {C3, C3}, c4 = {C4, C4},
              c5 = {C5, C5}, c6 = {C6, C6}, c7 = {C7, C7}, c8 = {C8, C8};
    float d   = fmaf(xin, s64, bk8);
    float dc  = __builtin_amdgcn_fmed3f(d, -30.0f, 78.0f);
    float x   = dc * L2E;
    float r   = __builtin_amdgcn_exp2f(x);
    float ri  = __builtin_amdgcn_exp2f(-x);
    float t1  = dc * QF;
    float A1  = __builtin_amdgcn_exp2f(-(t1 * t1));
    float t2  = fmaf(dc, QF, -16.0f * QF);
    float A2  = __builtin_amdgcn_exp2f(-(t2 * t2));
    float t3  = fmaf(dc, QF, -32.0f * QF);
    float A3  = __builtin_amdgcn_exp2f(-(t3 * t3));
    float t4  = fmaf(dc, QF, -48.0f * QF);
    float A4  = __builtin_amdgcn_exp2f(-(t4 * t4));
    v2f RRa = {r,        r * K16};
    v2f RRb = {r * K32,  r * K48};
    v2f RIa = {ri,       ri * K16I};
    v2f RIb = {ri * K32I, ri * K48I};
    v2f TA = {A1, A2}, TB = {A3, A4};
    v2f UA = TA, UB = TB;
    accA[8] += TA;  accB[8] += TB;                 // center bins (8,24,40,56)
    TA *= RRa; accA[9]  = __builtin_elementwise_fma(TA, c1, accA[9]);
    TB *= RRb; accB[9]  = __builtin_elementwise_fma(TB, c1, accB[9]);
    TA *= RRa; accA[10] = __builtin_elementwise_fma(TA, c2, accA[10]);
    TB *= RRb; accB[10] = __builtin_elementwise_fma(TB, c2, accB[10]);
    TA *= RRa; accA[11] = __builtin_elementwise_fma(TA, c3, accA[11]);
    TB *= RRb; accB[11] = __builtin_elementwise_fma(TB, c3, accB[11]);
    TA *= RRa; accA[12] = __builtin_elementwise_fma(TA, c4, accA[12]);
    TB *= RRb; accB[12] = __builtin_elementwise_fma(TB, c4, accB[12]);
    TA *= RRa; accA[13] = __builtin_elementwise_fma(TA, c5, accA[13]);
    TB *= RRb; accB[13] = __builtin_elementwise_fma(TB, c5, accB[13]);
    TA *= RRa; accA[14] = __builtin_elementwise_fma(TA, c6, accA[14]);
    TB *= RRb; accB[14] = __builtin_elementwise_fma(TB, c6, accB[14]);
    TA *= RRa; accA[15] = __builtin_elementwise_fma(TA, c7, accA[15]);
    TB *= RRb; accB[15] = __builtin_elementwise_fma(TB, c7, accB[15]);
    UA *= RIa; accA[7]  = __builtin_elementwise_fma(UA, c1, accA[7]);
    UB *= RIb; accB[7]  = __builtin_elementwise_fma(UB, c1, accB[7]);
    UA *= RIa; accA[6]  = __builtin_elementwise_fma(UA, c2, accA[6]);
    UB *= RIb; accB[6]  = __builtin_elementwise_fma(UB, c2, accB[6]);
    UA *= RIa; accA[5]  = __builtin_elementwise_fma(UA, c3, accA[5]);
    UB *= RIb; accB[5]  = __builtin_elementwise_fma(UB, c3, accB[5]);
    UA *= RIa; accA[4]  = __builtin_elementwise_fma(UA, c4, accA[4]);
    UB *= RIb; accB[4]  = __builtin_elementwise_fma(UB, c4, accB[4]);
    UA *= RIa; accA[3]  = __builtin_elementwise_fma(UA, c5, accA[3]);
    UB *= RIb; accB[3]  = __builtin_elementwise_fma(UB, c5, accB[3]);
    UA *= RIa; accA[2]  = __builtin_elementwise_fma(UA, c6, accA[2]);
    UB *= RIb; accB[2]  = __builtin_elementwise_fma(UB, c6, accB[2]);
    UA *= RIa; accA[1]  = __builtin_elementwise_fma(UA, c7, accA[1]);
    UB *= RIb; accB[1]  = __builtin_elementwise_fma(UB, c7, accB[1]);
    UA *= RIa; accA[0]  = __builtin_elementwise_fma(UA, c8, accA[0]);
    UB *= RIb; accB[0]  = __builtin_elementwise_fma(UB, c8, accB[0]);
}

// ---------- pass 2: hist (64 bins/wave, quarter-chunk/wave) + fused KL ----
__global__ __launch_bounds__(256, 4) void hist_k(const float4* __restrict__ pred,
                                                 const float4* __restrict__ tgt,
                                                 const float* __restrict__ mmn,
                                                 const float* __restrict__ mmx,
                                                 float* __restrict__ hist,
                                                 unsigned int* __restrict__ cnt,
                                                 float* __restrict__ out) {
    const int blk   = blockIdx.x;
    const int tens  = blk & 1;
    const int batch = (blk >> 1) & (NB - 1);
    const int chunk = blk >> 5;                      // 0..CB-1
    const int tid   = threadIdx.x;
    const int wave  = tid >> 6, lane = tid & 63;

    const int F4C = NPB / 4 / CB;                    // 1024 float4 per chunk
    const int F4Q = F4C / 4;                         // 256 per quarter (per wave)
    const float4* __restrict__ src = (tens ? tgt : pred)
        + (size_t)batch * (NPB / 4) + (size_t)chunk * F4C + (size_t)wave * F4Q;

    // issue first data load before the prologue reduction (overlap)
    float4 v = src[lane];

    // lane-parallel reduce of this batch's 64 minmax partials
    float vmin = mmn[batch * MMB + lane];
    float vmax = mmx[batch * MMB + lane];
    #pragma unroll
    for (int o = 1; o < 64; o <<= 1) {
        vmin = fminf(vmin, __shfl_xor(vmin, o));
        vmax = fmaxf(vmax, __shfl_xor(vmax, o));
    }
    const float s64 = 64.0f / (vmax - vmin + EPSF);
    const float bk8 = fmaf(-vmin, s64, -0.5f) - 8.0f;   // d = u - 8

    v2f accA[16], accB[16];
    #pragma unroll
    for (int k = 0; k < 16; ++k) {
        accA[k] = (v2f){0.0f, 0.0f};
        accB[k] = (v2f){0.0f, 0.0f};
    }

    const int NIT = F4Q / 64;                        // 4 wave-iterations
    #pragma unroll 1
    for (int it = 0; it < NIT; ++it) {
        // prefetch next iteration's data; latency hides under the burst
        float4 vn = src[(it < NIT - 1 ? (it + 1) * 64 : 0) + lane];
        point64(v.x, s64, bk8, accA, accB);
        point64(v.y, s64, bk8, accA, accB);
        point64(v.z, s64, bk8, accA, accB);
        point64(v.w, s64, bk8, accA, accB);
        v = vn;
    }

    // 6-step tree-exchange reduce over all 64 bins; step 0 fused with the
    // acc->val extraction. Bin map: accA[k].x = bin k, accA[k].y = bin
    // 16+k, accB[k].x = bin 32+k, accB[k].y = bin 48+k. Keep vk (bin
    // matching this lane's bit s), send vo (bin the partner keeps):
    // val[p] = vk + shfl_xor(vo, o). After step 5: val[0] = bin 'lane'.
    float val[32];
    {
        const bool b = lane & 1;
        #pragma unroll
        for (int p = 0; p < 8; ++p) {
            float lo, hi, vk, vo;
            lo = accA[2*p].x; hi = accA[2*p+1].x;       // bins (2p, 2p+1)
            vk = b ? hi : lo; vo = b ? lo : hi;
            val[p]      = vk + __shfl_xor(vo, 1);
            lo = accA[2*p].y; hi = accA[2*p+1].y;       // bins (16+2p, 17+2p)
            vk = b ? hi : lo; vo = b ? lo : hi;
            val[8 + p]  = vk + __shfl_xor(vo, 1);
            lo = accB[2*p].x; hi = accB[2*p+1].x;       // bins (32+2p, 33+2p)
            vk = b ? hi : lo; vo = b ? lo : hi;
            val[16 + p] = vk + __shfl_xor(vo, 1);
            lo = accB[2*p].y; hi = accB[2*p+1].y;       // bins (48+2p, 49+2p)
            vk = b ? hi : lo; vo = b ? lo : hi;
            val[24 + p] = vk + __shfl_xor(vo, 1);
        }
    }
    #pragma unroll
    for (int s = 1; s < 6; ++s) {
        const int o = 1 << s;
        const bool b = (lane >> s) & 1;
        #pragma unroll
        for (int p = 0; p < (32 >> s); ++p) {
            float lo = val[2 * p], hi = val[2 * p + 1];
            float vk = b ? hi : lo;          // bin this lane keeps
            float vo = b ? lo : hi;          // bin the partner keeps
            val[p] = vk + __shfl_xor(vo, o);
        }
    }
    unsafeAtomicAdd(&hist[(tens * NB + batch) * NBINS + lane], val[0]);

    // ---- last-block-done: fold final KL into this dispatch ----
    __syncthreads();                 // drains all 256 bin atomics (vmcnt(0))
    __shared__ unsigned int slast;
    if (tid == 0) {
        __threadfence();             // release: bin atomics visible device-wide
        slast = (atomicAdd(cnt, 1u) == 2u * NB * CB - 1u) ? 1u : 0u;
    }
    __syncthreads();
    if (slast) {
        __threadfence();             // acquire: see all other blocks' atomics
        __shared__ float wacc[4];
        float a = 0.0f;
        for (int b = wave; b < NB; b += 4) {
            float hp = AG_LOAD(&hist[b * NBINS + lane]);
            float ht = AG_LOAD(&hist[(NB + b) * NBINS + lane]);
            float sp = hp, st = ht;
            #pragma unroll
            for (int o = 1; o < 64; o <<= 1) {
                sp += __shfl_xor(sp, o);
                st += __shfl_xor(st, o);
            }
            float pp = hp / (sp + EPSF);
            float pt = ht / (st + EPSF);
            float term = pt * ((__builtin_amdgcn_logf(pt + EPSF)
                              - __builtin_amdgcn_logf(pp + EPSF)) * LN2);
            #pragma unroll
            for (int o = 1; o < 64; o <<= 1) term += __shfl_xor(term, o);
            a += term;
        }
        if (lane == 0) wacc[wave] = a;
        __syncthreads();
        if (tid == 0)
            out[0] = 0.1f * (wacc[0] + wacc[1] + wacc[2] + wacc[3]) / (float)NB;
    }
}

extern "C" void kernel_launch(void* const* d_in, const int* in_sizes, int n_in,
                              void* d_out, int out_size, void* d_ws, size_t ws_size,
                              hipStream_t stream) {
    const float* pred = (const float*)d_in[0];
    const float* tgt  = (const float*)d_in[1];
    float* mmn  = (float*)d_ws;
    float* mmx  = mmn + NB * MMB;
    float* hist = mmx + NB * MMB;
    unsigned int* cnt = (unsigned int*)(hist + 2 * NB * NBINS);
    float* out  = (float*)d_out;

    minmax_k<<<NB * MMB, 256, 0, stream>>>((const float4*)tgt, mmn, mmx, hist, cnt);
    hist_k  <<<2 * NB * CB, 256, 0, stream>>>((const float4*)pred, (const float4*)tgt,
                                              mmn, mmx, hist, cnt, (float*)d_out);
}

// Round 12
// 134.205 us; speedup vs baseline: 5.5119x; 1.0683x over previous
//
#include <hip/hip_runtime.h>
#include <math.h>

// Problem constants
#define NB    16            // batches
#define NPB   (512*512)     // elements per batch
#define NBINS 64
#define MMB   64            // minmax blocks per batch (grid 1024 = 4/CU)
#define CB    64            // hist chunks per (tensor,batch) -> grid 2*16*64 = 2048
#define EPSF  1e-8f
#define QF    0.84932180517f   // sqrt(0.5*log2(e)); exp(-d^2/2) = exp2(-(q*d)^2)
#define L2E   1.44269504089f   // log2(e)
#define LN2   0.69314718056f
#define K16   1.12535175e-7f   // e^-16
#define K16I  8886110.5f       // e^+16
#define K32   1.26641655e-14f  // e^-32
#define K32I  7.8962960e13f    // e^+32
#define K48   1.42516408e-21f  // e^-48
#define K48I  7.01673591e20f   // e^+48

// R29 = R28 last-block-done fusion, spill + fence pathologies fixed.
// R28 evidence: VGPR_Count 56 < 64 live acc floats -> inlined KL tail
// perturbed regalloc into spilling the accumulators (hist 34 -> ~100 us,
// VALUBusy 21%). Protocol itself was CORRECT (absmax 0.0). Fixes:
// (1) KL tail in a noinline device function -> own regalloc frame; acc
//     dead at call site, main body keeps ~100 VGPR.
// (2) threadfences removed: bin adds are device-scope atomics, drained by
//     __syncthreads (vmcnt(0) before s_barrier); cnt bump is a RELEASE
//     agent-scope RMW; last block reads hist via agent-scope loads (G16).
//     No full L2 writeback per block.
// cnt re-zeroed by minmax_k every launch -> graph-replay safe.

typedef float v2f __attribute__((ext_vector_type(2)));

#define AG_LOAD(p) __hip_atomic_load((p), __ATOMIC_RELAXED, __HIP_MEMORY_SCOPE_AGENT)

// ws layout: mmn[1024] | mmx[1024] | hist[2][16][64] | cnt[1]

// ---------- pass 1: per-batch block-level min/max (zeroes hist + cnt) ----------
__global__ __launch_bounds__(256) void minmax_k(const float4* __restrict__ tgt,
                                                float* __restrict__ mmn,
                                                float* __restrict__ mmx,
                                                float* __restrict__ hist,
                                                unsigned int* __restrict__ cnt) {
    const int batch = blockIdx.x / MMB, sub = blockIdx.x % MMB;
    if (sub == 0 && threadIdx.x < 128) {
        const int tens = threadIdx.x >> 6, lane = threadIdx.x & 63;
        hist[(tens * NB + batch) * NBINS + lane] = 0.0f;
    }
    if (blockIdx.x == 0 && threadIdx.x == 0) cnt[0] = 0u;

    const int F4 = NPB / 4 / MMB;              // 1024 float4 per block
    const float4* p = tgt + (size_t)batch * (NPB / 4) + (size_t)sub * F4;
    float mn = 3.4e38f, mx = -3.4e38f;
    #pragma unroll
    for (int i = 0; i < F4 / 256; ++i) {       // 4 iterations
        float4 v = p[i * 256 + threadIdx.x];
        mn = fminf(mn, fminf(fminf(v.x, v.y), fminf(v.z, v.w)));
        mx = fmaxf(mx, fmaxf(fmaxf(v.x, v.y), fmaxf(v.z, v.w)));
    }
    #pragma unroll
    for (int o = 1; o < 64; o <<= 1) {
        mn = fminf(mn, __shfl_xor(mn, o));
        mx = fmaxf(mx, __shfl_xor(mx, o));
    }
    __shared__ float smn[4], smx[4];
    const int wave = threadIdx.x >> 6, lane = threadIdx.x & 63;
    if (lane == 0) { smn[wave] = mn; smx[wave] = mx; }
    __syncthreads();
    if (threadIdx.x == 0) {
        mmn[blockIdx.x] = fminf(fminf(smn[0], smn[1]), fminf(smn[2], smn[3]));
        mmx[blockIdx.x] = fmaxf(fmaxf(smx[0], smx[1]), fmaxf(smx[2], smx[3]));
    }
}

// ---------- per-point update of ALL 64 bins, 4 packed anchors ----------
// d = u - 8. Anchor m in {8,24,40,56} covers bins m-8..m+7:
// E(m+i) = A_m * rho_m^i * C_i, A_m = e^{-(d-(m-8))^2/2}, rho_m = e^d * e^{-(m-8)}.
// accA[k] = bins (k, 16+k); accB[k] = bins (32+k, 48+k), k = 0..15.
// Clamp [-30,78]: at bounds max rate e^78 finite, amplitudes underflow to 0;
// clamp only bites where true contribution <= e^-242.
__device__ __forceinline__ void point64(float xin, float s64, float bk8,
                                        v2f* __restrict__ accA,
                                        v2f* __restrict__ accB) {
    const float C1 = 0.60653065971f,    C2 = 0.13533528324f,
                C3 = 0.01110899654f,    C4 = 3.35462627903e-4f,
                C5 = 3.72665317208e-6f, C6 = 1.52299797447e-8f,
                C7 = 2.28973484833e-11f, C8 = 1.26641655490e-14f;
    const v2f c1 = {C1, C1}, c2 = {C2, C2}, c3 = {C3, C3}, c4 = {C4, C4},
              c5 = {C5, C5}, c6 = {C6, C6}, c7 = {C7, C7}, c8 = {C8, C8};
    float d   = fmaf(xin, s64, bk8);
    float dc  = __builtin_amdgcn_fmed3f(d, -30.0f, 78.0f);
    float x   = dc * L2E;
    float r   = __builtin_amdgcn_exp2f(x);
    float ri  = __builtin_amdgcn_exp2f(-x);
    float t1  = dc * QF;
    float A1  = __builtin_amdgcn_exp2f(-(t1 * t1));
    float t2  = fmaf(dc, QF, -16.0f * QF);
    float A2  = __builtin_amdgcn_exp2f(-(t2 * t2));
    float t3  = fmaf(dc, QF, -32.0f * QF);
    float A3  = __builtin_amdgcn_exp2f(-(t3 * t3));
    float t4  = fmaf(dc, QF, -48.0f * QF);
    float A4  = __builtin_amdgcn_exp2f(-(t4 * t4));
    v2f RRa = {r,        r * K16};
    v2f RRb = {r * K32,  r * K48};
    v2f RIa = {ri,       ri * K16I};
    v2f RIb = {ri * K32I, ri * K48I};
    v2f TA = {A1, A2}, TB = {A3, A4};
    v2f UA = TA, UB = TB;
    accA[8] += TA;  accB[8] += TB;                 // center bins (8,24,40,56)
    TA *= RRa; accA[9]  = __builtin_elementwise_fma(TA, c1, accA[9]);
    TB *= RRb; accB[9]  = __builtin_elementwise_fma(TB, c1, accB[9]);
    TA *= RRa; accA[10] = __builtin_elementwise_fma(TA, c2, accA[10]);
    TB *= RRb; accB[10] = __builtin_elementwise_fma(TB, c2, accB[10]);
    TA *= RRa; accA[11] = __builtin_elementwise_fma(TA, c3, accA[11]);
    TB *= RRb; accB[11] = __builtin_elementwise_fma(TB, c3, accB[11]);
    TA *= RRa; accA[12] = __builtin_elementwise_fma(TA, c4, accA[12]);
    TB *= RRb; accB[12] = __builtin_elementwise_fma(TB, c4, accB[12]);
    TA *= RRa; accA[13] = __builtin_elementwise_fma(TA, c5, accA[13]);
    TB *= RRb; accB[13] = __builtin_elementwise_fma(TB, c5, accB[13]);
    TA *= RRa; accA[14] = __builtin_elementwise_fma(TA, c6, accA[14]);
    TB *= RRb; accB[14] = __builtin_elementwise_fma(TB, c6, accB[14]);
    TA *= RRa; accA[15] = __builtin_elementwise_fma(TA, c7, accA[15]);
    TB *= RRb; accB[15] = __builtin_elementwise_fma(TB, c7, accB[15]);
    UA *= RIa; accA[7]  = __builtin_elementwise_fma(UA, c1, accA[7]);
    UB *= RIb; accB[7]  = __builtin_elementwise_fma(UB, c1, accB[7]);
    UA *= RIa; accA[6]  = __builtin_elementwise_fma(UA, c2, accA[6]);
    UB *= RIb; accB[6]  = __builtin_elementwise_fma(UB, c2, accB[6]);
    UA *= RIa; accA[5]  = __builtin_elementwise_fma(UA, c3, accA[5]);
    UB *= RIb; accB[5]  = __builtin_elementwise_fma(UB, c3, accB[5]);
    UA *= RIa; accA[4]  = __builtin_elementwise_fma(UA, c4, accA[4]);
    UB *= RIb; accB[4]  = __builtin_elementwise_fma(UB, c4, accB[4]);
    UA *= RIa; accA[3]  = __builtin_elementwise_fma(UA, c5, accA[3]);
    UB *= RIb; accB[3]  = __builtin_elementwise_fma(UB, c5, accB[3]);
    UA *= RIa; accA[2]  = __builtin_elementwise_fma(UA, c6, accA[2]);
    UB *= RIb; accB[2]  = __builtin_elementwise_fma(UB, c6, accB[2]);
    UA *= RIa; accA[1]  = __builtin_elementwise_fma(UA, c7, accA[1]);
    UB *= RIb; accB[1]  = __builtin_elementwise_fma(UB, c7, accB[1]);
    UA *= RIa; accA[0]  = __builtin_elementwise_fma(UA, c8, accA[0]);
    UB *= RIb; accB[0]  = __builtin_elementwise_fma(UB, c8, accB[0]);
}

// ---------- KL tail: own regalloc frame (noinline) so it cannot perturb
// the hist body's accumulator allocation (R28 lesson: inlined tail -> 56
// VGPR -> acc spilled to scratch, 3x regression). Called by the one block
// that sees cnt == 2047; all its threads enter (block-uniform condition),
// so __syncthreads inside is legal.
__device__ __attribute__((noinline)) void kl_tail(float* __restrict__ hist,
                                                  float* __restrict__ out,
                                                  int tid, int wave, int lane) {
    __shared__ float wacc[4];
    float a = 0.0f;
    for (int b = wave; b < NB; b += 4) {
        float hp = AG_LOAD(&hist[b * NBINS + lane]);
        float ht = AG_LOAD(&hist[(NB + b) * NBINS + lane]);
        float sp = hp, st = ht;
        #pragma unroll
        for (int o = 1; o < 64; o <<= 1) {
            sp += __shfl_xor(sp, o);
            st += __shfl_xor(st, o);
        }
        float pp = hp / (sp + EPSF);
        float pt = ht / (st + EPSF);
        float term = pt * ((__builtin_amdgcn_logf(pt + EPSF)
                          - __builtin_amdgcn_logf(pp + EPSF)) * LN2);
        #pragma unroll
        for (int o = 1; o < 64; o <<= 1) term += __shfl_xor(term, o);
        a += term;
    }
    if (lane == 0) wacc[wave] = a;
    __syncthreads();
    if (tid == 0)
        out[0] = 0.1f * (wacc[0] + wacc[1] + wacc[2] + wacc[3]) / (float)NB;
}

// ---------- pass 2: hist (64 bins/wave, quarter-chunk/wave) + fused KL ----
__global__ __launch_bounds__(256, 4) void hist_k(const float4* __restrict__ pred,
                                                 const float4* __restrict__ tgt,
                                                 const float* __restrict__ mmn,
                                                 const float* __restrict__ mmx,
                                                 float* __restrict__ hist,
                                                 unsigned int* __restrict__ cnt,
                                                 float* __restrict__ out) {
    const int blk   = blockIdx.x;
    const int tens  = blk & 1;
    const int batch = (blk >> 1) & (NB - 1);
    const int chunk = blk >> 5;                      // 0..CB-1
    const int tid   = threadIdx.x;
    const int wave  = tid >> 6, lane = tid & 63;

    const int F4C = NPB / 4 / CB;                    // 1024 float4 per chunk
    const int F4Q = F4C / 4;                         // 256 per quarter (per wave)
    const float4* __restrict__ src = (tens ? tgt : pred)
        + (size_t)batch * (NPB / 4) + (size_t)chunk * F4C + (size_t)wave * F4Q;

    // issue first data load before the prologue reduction (overlap)
    float4 v = src[lane];

    // lane-parallel reduce of this batch's 64 minmax partials
    float vmin = mmn[batch * MMB + lane];
    float vmax = mmx[batch * MMB + lane];
    #pragma unroll
    for (int o = 1; o < 64; o <<= 1) {
        vmin = fminf(vmin, __shfl_xor(vmin, o));
        vmax = fmaxf(vmax, __shfl_xor(vmax, o));
    }
    const float s64 = 64.0f / (vmax - vmin + EPSF);
    const float bk8 = fmaf(-vmin, s64, -0.5f) - 8.0f;   // d = u - 8

    v2f accA[16], accB[16];
    #pragma unroll
    for (int k = 0; k < 16; ++k) {
        accA[k] = (v2f){0.0f, 0.0f};
        accB[k] = (v2f){0.0f, 0.0f};
    }

    const int NIT = F4Q / 64;                        // 4 wave-iterations
    #pragma unroll 1
    for (int it = 0; it < NIT; ++it) {
        // prefetch next iteration's data; latency hides under the burst
        float4 vn = src[(it < NIT - 1 ? (it + 1) * 64 : 0) + lane];
        point64(v.x, s64, bk8, accA, accB);
        point64(v.y, s64, bk8, accA, accB);
        point64(v.z, s64, bk8, accA, accB);
        point64(v.w, s64, bk8, accA, accB);
        v = vn;
    }

    // 6-step tree-exchange reduce over all 64 bins; step 0 fused with the
    // acc->val extraction. Bin map: accA[k].x = bin k, accA[k].y = bin
    // 16+k, accB[k].x = bin 32+k, accB[k].y = bin 48+k. Keep vk (bin
    // matching this lane's bit s), send vo (bin the partner keeps):
    // val[p] = vk + shfl_xor(vo, o). After step 5: val[0] = bin 'lane'.
    float val[32];
    {
        const bool b = lane & 1;
        #pragma unroll
        for (int p = 0; p < 8; ++p) {
            float lo, hi, vk, vo;
            lo = accA[2*p].x; hi = accA[2*p+1].x;       // bins (2p, 2p+1)
            vk = b ? hi : lo; vo = b ? lo : hi;
            val[p]      = vk + __shfl_xor(vo, 1);
            lo = accA[2*p].y; hi = accA[2*p+1].y;       // bins (16+2p, 17+2p)
            vk = b ? hi : lo; vo = b ? lo : hi;
            val[8 + p]  = vk + __shfl_xor(vo, 1);
            lo = accB[2*p].x; hi = accB[2*p+1].x;       // bins (32+2p, 33+2p)
            vk = b ? hi : lo; vo = b ? lo : hi;
            val[16 + p] = vk + __shfl_xor(vo, 1);
            lo = accB[2*p].y; hi = accB[2*p+1].y;       // bins (48+2p, 49+2p)
            vk = b ? hi : lo; vo = b ? lo : hi;
            val[24 + p] = vk + __shfl_xor(vo, 1);
        }
    }
    #pragma unroll
    for (int s = 1; s < 6; ++s) {
        const int o = 1 << s;
        const bool b = (lane >> s) & 1;
        #pragma unroll
        for (int p = 0; p < (32 >> s); ++p) {
            float lo = val[2 * p], hi = val[2 * p + 1];
            float vk = b ? hi : lo;          // bin this lane keeps
            float vo = b ? lo : hi;          // bin the partner keeps
            val[p] = vk + __shfl_xor(vo, o);
        }
    }
    unsafeAtomicAdd(&hist[(tens * NB + batch) * NBINS + lane], val[0]);

    // ---- last-block-done: fold final KL into this dispatch ----
    // __syncthreads drains this block's 256 bin atomics (vmcnt(0) before
    // s_barrier) -> they are complete at the coherence point. The cnt bump
    // is a RELEASE agent-scope RMW (ordering without full-cache fence).
    __syncthreads();
    __shared__ unsigned int slast;
    if (tid == 0)
        slast = (__hip_atomic_fetch_add(cnt, 1u, __ATOMIC_RELEASE,
                                        __HIP_MEMORY_SCOPE_AGENT)
                 == 2u * NB * CB - 1u) ? 1u : 0u;
    __syncthreads();
    if (slast) kl_tail(hist, out, tid, wave, lane);
}

extern "C" void kernel_launch(void* const* d_in, const int* in_sizes, int n_in,
                              void* d_out, int out_size, void* d_ws, size_t ws_size,
                              hipStream_t stream) {
    const float* pred = (const float*)d_in[0];
    const float* tgt  = (const float*)d_in[1];
    float* mmn  = (float*)d_ws;
    float* mmx  = mmn + NB * MMB;
    float* hist = mmx + NB * MMB;
    unsigned int* cnt = (unsigned int*)(hist + 2 * NB * NBINS);

    minmax_k<<<NB * MMB, 256, 0, stream>>>((const float4*)tgt, mmn, mmx, hist, cnt);
    hist_k  <<<2 * NB * CB, 256, 0, stream>>>((const float4*)pred, (const float4*)tgt,
                                              mmn, mmx, hist, cnt, (float*)d_out);
}

// Round 13
// 102.950 us; speedup vs baseline: 7.1853x; 1.3036x over previous
//
#include <hip/hip_runtime.h>
#include <math.h>

// Problem constants
#define NB    16            // batches
#define NPB   (512*512)     // elements per batch
#define NBINS 64
#define MMB   64            // minmax blocks per batch (grid 1024 = 4/CU)
#define CB    32            // hist chunks per (tensor,batch) -> grid 2*16*32 = 1024
#define EPSF  1e-8f
#define QF    0.84932180517f   // sqrt(0.5*log2(e)); exp(-d^2/2) = exp2(-(q*d)^2)
#define L2E   1.44269504089f   // log2(e)
#define LN2   0.69314718056f
#define K16   1.12535175e-7f   // e^-16
#define K16I  8886110.5f       // e^+16
#define K32   1.26641655e-14f  // e^-32
#define K32I  7.8962960e13f    // e^+32
#define K48   1.42516408e-21f  // e^-48
#define K48I  7.01673591e20f   // e^+48

// R30 = R26 revert (proven 102.7 us) + CB 64->32. In-dispatch KL fusion is
// CLOSED: R28 (inline) and R29 (noinline ABI call) both collapse hist_k to
// 56 VGPR + acc spill (~95 us) -- any tail call path poisons regalloc.
// CB=32: same total chain work, but per-block overhead (prologue reduce,
// 6-step tree, bin atomics) halves; grid 1024 = exactly 4 blocks/CU, one
// clean block-wave. Regrouping-safe: R22/R25/R26 all absmax 0.0 across
// different per-wave groupings. Budget: fill ~44 (harness) + minmax ~7 +
// hist ~34 + final ~4 + gaps ~14.

typedef float v2f __attribute__((ext_vector_type(2)));

// ws layout: mmn[1024] | mmx[1024] | hist[2][16][64]

// ---------- pass 1: per-batch block-level min/max (also zeroes hist) ----------
__global__ __launch_bounds__(256) void minmax_k(const float4* __restrict__ tgt,
                                                float* __restrict__ mmn,
                                                float* __restrict__ mmx,
                                                float* __restrict__ hist) {
    const int batch = blockIdx.x / MMB, sub = blockIdx.x % MMB;
    if (sub == 0 && threadIdx.x < 128) {
        const int tens = threadIdx.x >> 6, lane = threadIdx.x & 63;
        hist[(tens * NB + batch) * NBINS + lane] = 0.0f;
    }

    const int F4 = NPB / 4 / MMB;              // 1024 float4 per block
    const float4* p = tgt + (size_t)batch * (NPB / 4) + (size_t)sub * F4;
    float mn = 3.4e38f, mx = -3.4e38f;
    #pragma unroll
    for (int i = 0; i < F4 / 256; ++i) {       // 4 iterations
        float4 v = p[i * 256 + threadIdx.x];
        mn = fminf(mn, fminf(fminf(v.x, v.y), fminf(v.z, v.w)));
        mx = fmaxf(mx, fmaxf(fmaxf(v.x, v.y), fmaxf(v.z, v.w)));
    }
    #pragma unroll
    for (int o = 1; o < 64; o <<= 1) {
        mn = fminf(mn, __shfl_xor(mn, o));
        mx = fmaxf(mx, __shfl_xor(mx, o));
    }
    __shared__ float smn[4], smx[4];
    const int wave = threadIdx.x >> 6, lane = threadIdx.x & 63;
    if (lane == 0) { smn[wave] = mn; smx[wave] = mx; }
    __syncthreads();
    if (threadIdx.x == 0) {
        mmn[blockIdx.x] = fminf(fminf(smn[0], smn[1]), fminf(smn[2], smn[3]));
        mmx[blockIdx.x] = fmaxf(fmaxf(smx[0], smx[1]), fmaxf(smx[2], smx[3]));
    }
}

// ---------- per-point update of ALL 64 bins, 4 packed anchors ----------
// d = u - 8. Anchor m in {8,24,40,56} covers bins m-8..m+7:
// E(m+i) = A_m * rho_m^i * C_i, A_m = e^{-(d-(m-8))^2/2}, rho_m = e^d * e^{-(m-8)}.
// accA[k] = bins (k, 16+k); accB[k] = bins (32+k, 48+k), k = 0..15.
// Clamp [-30,78]: at bounds max rate e^78 finite, amplitudes underflow to 0;
// clamp only bites where true contribution <= e^-242.
__device__ __forceinline__ void point64(float xin, float s64, float bk8,
                                        v2f* __restrict__ accA,
                                        v2f* __restrict__ accB) {
    const float C1 = 0.60653065971f,    C2 = 0.13533528324f,
                C3 = 0.01110899654f,    C4 = 3.35462627903e-4f,
                C5 = 3.72665317208e-6f, C6 = 1.52299797447e-8f,
                C7 = 2.28973484833e-11f, C8 = 1.26641655490e-14f;
    const v2f c1 = {C1, C1}, c2 = {C2, C2}, c3 = {C3, C3}, c4 = {C4, C4},
              c5 = {C5, C5}, c6 = {C6, C6}, c7 = {C7, C7}, c8 = {C8, C8};
    float d   = fmaf(xin, s64, bk8);
    float dc  = __builtin_amdgcn_fmed3f(d, -30.0f, 78.0f);
    float x   = dc * L2E;
    float r   = __builtin_amdgcn_exp2f(x);
    float ri  = __builtin_amdgcn_exp2f(-x);
    float t1  = dc * QF;
    float A1  = __builtin_amdgcn_exp2f(-(t1 * t1));
    float t2  = fmaf(dc, QF, -16.0f * QF);
    float A2  = __builtin_amdgcn_exp2f(-(t2 * t2));
    float t3  = fmaf(dc, QF, -32.0f * QF);
    float A3  = __builtin_amdgcn_exp2f(-(t3 * t3));
    float t4  = fmaf(dc, QF, -48.0f * QF);
    float A4  = __builtin_amdgcn_exp2f(-(t4 * t4));
    v2f RRa = {r,        r * K16};
    v2f RRb = {r * K32,  r * K48};
    v2f RIa = {ri,       ri * K16I};
    v2f RIb = {ri * K32I, ri * K48I};
    v2f TA = {A1, A2}, TB = {A3, A4};
    v2f UA = TA, UB = TB;
    accA[8] += TA;  accB[8] += TB;                 // center bins (8,24,40,56)
    TA *= RRa; accA[9]  = __builtin_elementwise_fma(TA, c1, accA[9]);
    TB *= RRb; accB[9]  = __builtin_elementwise_fma(TB, c1, accB[9]);
    TA *= RRa; accA[10] = __builtin_elementwise_fma(TA, c2, accA[10]);
    TB *= RRb; accB[10] = __builtin_elementwise_fma(TB, c2, accB[10]);
    TA *= RRa; accA[11] = __builtin_elementwise_fma(TA, c3, accA[11]);
    TB *= RRb; accB[11] = __builtin_elementwise_fma(TB, c3, accB[11]);
    TA *= RRa; accA[12] = __builtin_elementwise_fma(TA, c4, accA[12]);
    TB *= RRb; accB[12] = __builtin_elementwise_fma(TB, c4, accB[12]);
    TA *= RRa; accA[13] = __builtin_elementwise_fma(TA, c5, accA[13]);
    TB *= RRb; accB[13] = __builtin_elementwise_fma(TB, c5, accB[13]);
    TA *= RRa; accA[14] = __builtin_elementwise_fma(TA, c6, accA[14]);
    TB *= RRb; accB[14] = __builtin_elementwise_fma(TB, c6, accB[14]);
    TA *= RRa; accA[15] = __builtin_elementwise_fma(TA, c7, accA[15]);
    TB *= RRb; accB[15] = __builtin_elementwise_fma(TB, c7, accB[15]);
    UA *= RIa; accA[7]  = __builtin_elementwise_fma(UA, c1, accA[7]);
    UB *= RIb; accB[7]  = __builtin_elementwise_fma(UB, c1, accB[7]);
    UA *= RIa; accA[6]  = __builtin_elementwise_fma(UA, c2, accA[6]);
    UB *= RIb; accB[6]  = __builtin_elementwise_fma(UB, c2, accB[6]);
    UA *= RIa; accA[5]  = __builtin_elementwise_fma(UA, c3, accA[5]);
    UB *= RIb; accB[5]  = __builtin_elementwise_fma(UB, c3, accB[5]);
    UA *= RIa; accA[4]  = __builtin_elementwise_fma(UA, c4, accA[4]);
    UB *= RIb; accB[4]  = __builtin_elementwise_fma(UB, c4, accB[4]);
    UA *= RIa; accA[3]  = __builtin_elementwise_fma(UA, c5, accA[3]);
    UB *= RIb; accB[3]  = __builtin_elementwise_fma(UB, c5, accB[3]);
    UA *= RIa; accA[2]  = __builtin_elementwise_fma(UA, c6, accA[2]);
    UB *= RIb; accB[2]  = __builtin_elementwise_fma(UB, c6, accB[2]);
    UA *= RIa; accA[1]  = __builtin_elementwise_fma(UA, c7, accA[1]);
    UB *= RIb; accB[1]  = __builtin_elementwise_fma(UB, c7, accB[1]);
    UA *= RIa; accA[0]  = __builtin_elementwise_fma(UA, c8, accA[0]);
    UB *= RIb; accB[0]  = __builtin_elementwise_fma(UB, c8, accB[0]);
}

// ---------- pass 2: gather histogram, 64 bins/wave, quarter-chunk/wave ----
__global__ __launch_bounds__(256, 4) void hist_k(const float4* __restrict__ pred,
                                                 const float4* __restrict__ tgt,
                                                 const float* __restrict__ mmn,
                                                 const float* __restrict__ mmx,
                                                 float* __restrict__ hist) {
    const int blk   = blockIdx.x;
    const int tens  = blk & 1;
    const int batch = (blk >> 1) & (NB - 1);
    const int chunk = blk >> 5;                      // 0..CB-1
    const int wave  = threadIdx.x >> 6, lane = threadIdx.x & 63;

    const int F4C = NPB / 4 / CB;                    // 2048 float4 per chunk
    const int F4Q = F4C / 4;                         // 512 per quarter (per wave)
    const float4* __restrict__ src = (tens ? tgt : pred)
        + (size_t)batch * (NPB / 4) + (size_t)chunk * F4C + (size_t)wave * F4Q;

    // issue first data load before the prologue reduction (overlap)
    float4 v = src[lane];

    // lane-parallel reduce of this batch's 64 minmax partials
    float vmin = mmn[batch * MMB + lane];
    float vmax = mmx[batch * MMB + lane];
    #pragma unroll
    for (int o = 1; o < 64; o <<= 1) {
        vmin = fminf(vmin, __shfl_xor(vmin, o));
        vmax = fmaxf(vmax, __shfl_xor(vmax, o));
    }
    const float s64 = 64.0f / (vmax - vmin + EPSF);
    const float bk8 = fmaf(-vmin, s64, -0.5f) - 8.0f;   // d = u - 8

    v2f accA[16], accB[16];
    #pragma unroll
    for (int k = 0; k < 16; ++k) {
        accA[k] = (v2f){0.0f, 0.0f};
        accB[k] = (v2f){0.0f, 0.0f};
    }

    const int NIT = F4Q / 64;                        // 8 wave-iterations
    #pragma unroll 1
    for (int it = 0; it < NIT; ++it) {
        // prefetch next iteration's data; latency hides under the burst
        float4 vn = src[(it < NIT - 1 ? (it + 1) * 64 : 0) + lane];
        point64(v.x, s64, bk8, accA, accB);
        point64(v.y, s64, bk8, accA, accB);
        point64(v.z, s64, bk8, accA, accB);
        point64(v.w, s64, bk8, accA, accB);
        v = vn;
    }

    // 6-step tree-exchange reduce over all 64 bins; step 0 fused with the
    // acc->val extraction. Bin map: accA[k].x = bin k, accA[k].y = bin
    // 16+k, accB[k].x = bin 32+k, accB[k].y = bin 48+k. Keep vk (bin
    // matching this lane's bit s), send vo (bin the partner keeps):
    // val[p] = vk + shfl_xor(vo, o). After step 5: val[0] = bin 'lane'.
    float val[32];
    {
        const bool b = lane & 1;
        #pragma unroll
        for (int p = 0; p < 8; ++p) {
            float lo, hi, vk, vo;
            lo = accA[2*p].x; hi = accA[2*p+1].x;       // bins (2p, 2p+1)
            vk = b ? hi : lo; vo = b ? lo : hi;
            val[p]      = vk + __shfl_xor(vo, 1);
            lo = accA[2*p].y; hi = accA[2*p+1].y;       // bins (16+2p, 17+2p)
            vk = b ? hi : lo; vo = b ? lo : hi;
            val[8 + p]  = vk + __shfl_xor(vo, 1);
            lo = accB[2*p].x; hi = accB[2*p+1].x;       // bins (32+2p, 33+2p)
            vk = b ? hi : lo; vo = b ? lo : hi;
            val[16 + p] = vk + __shfl_xor(vo, 1);
            lo = accB[2*p].y; hi = accB[2*p+1].y;       // bins (48+2p, 49+2p)
            vk = b ? hi : lo; vo = b ? lo : hi;
            val[24 + p] = vk + __shfl_xor(vo, 1);
        }
    }
    #pragma unroll
    for (int s = 1; s < 6; ++s) {
        const int o = 1 << s;
        const bool b = (lane >> s) & 1;
        #pragma unroll
        for (int p = 0; p < (32 >> s); ++p) {
            float lo = val[2 * p], hi = val[2 * p + 1];
            float vk = b ? hi : lo;          // bin this lane keeps
            float vo = b ? lo : hi;          // bin the partner keeps
            val[p] = vk + __shfl_xor(vo, o);
        }
    }
    unsafeAtomicAdd(&hist[(tens * NB + batch) * NBINS + lane], val[0]);
}

// ---------- pass 3: KL (fp32, v_log), tiny ----------
__global__ __launch_bounds__(256) void final_k(const float* __restrict__ hist,
                                               float* __restrict__ out) {
    const int lane = threadIdx.x & 63, wave = threadIdx.x >> 6;
    __shared__ float wacc[4];
    float a = 0.0f;
    for (int b = wave; b < NB; b += 4) {
        float hp = hist[b * NBINS + lane];
        float ht = hist[(NB + b) * NBINS + lane];
        float sp = hp, st = ht;
        #pragma unroll
        for (int o = 1; o < 64; o <<= 1) {
            sp += __shfl_xor(sp, o);
            st += __shfl_xor(st, o);
        }
        float pp = hp / (sp + EPSF);
        float pt = ht / (st + EPSF);
        float term = pt * ((__builtin_amdgcn_logf(pt + EPSF)
                          - __builtin_amdgcn_logf(pp + EPSF)) * LN2);
        #pragma unroll
        for (int o = 1; o < 64; o <<= 1) term += __shfl_xor(term, o);
        a += term;
    }
    if (lane == 0) wacc[wave] = a;
    __syncthreads();
    if (threadIdx.x == 0)
        out[0] = 0.1f * (wacc[0] + wacc[1] + wacc[2] + wacc[3]) / (float)NB;
}

extern "C" void kernel_launch(void* const* d_in, const int* in_sizes, int n_in,
                              void* d_out, int out_size, void* d_ws, size_t ws_size,
                              hipStream_t stream) {
    const float* pred = (const float*)d_in[0];
    const float* tgt  = (const float*)d_in[1];
    float* mmn  = (float*)d_ws;
    float* mmx  = mmn + NB * MMB;
    float* hist = mmx + NB * MMB;
    float* out  = (float*)d_out;

    minmax_k<<<NB * MMB, 256, 0, stream>>>((const float4*)tgt, mmn, mmx, hist);
    hist_k  <<<2 * NB * CB, 256, 0, stream>>>((const float4*)pred, (const float4*)tgt,
                                              mmn, mmx, hist);
    final_k <<<1, 256, 0, stream>>>(hist, out);
}